// Round 3
// baseline (58.488 us; speedup 1.0000x reference)
//
#include <hip/hip_runtime.h>
#include <hip/hip_cooperative_groups.h>
#include <math.h>

namespace cg = cooperative_groups;

#define S2 64
#define HH 128
#define WW 128
#define BB 16
#define TIK 0.05f
#define NU 33           // uu = 0..32; uu=1..31 also emit the mirror row u=64-uu
#define NBLK (BB * NU)  // 528 blocks

// Single cooperative kernel. One block per (b,uu), 256 threads.
// freq symmetry: freq[64-u] = -freq[u]  =>  Cr mirror-even, Ci mirror-odd.
// Phase B keeps the 4 cross-sums (c*Cr, s*Cr, c*Ci, s*Ci) separate so both
// u-rows come out of the same 4 FMA/step.
__global__ __launch_bounds__(256) void chf_fused(const float* __restrict__ dnn,
                                                 const float* __restrict__ chf,
                                                 float* __restrict__ partials,
                                                 float* __restrict__ out) {
    const int bid = blockIdx.x;
    const int b = bid / NU;
    const int uu = bid - b * NU;     // 0..32
    const int t = threadIdx.x;       // 0..255

    __shared__ float cb[HH], sb[HH];            // cos/sin(fu*(h+0.5))
    __shared__ float a2r[8 * WW], a2i[8 * WW];  // phase-A h-group partials
    __shared__ float crw[WW], ciw[WW];          // stage-A outputs
    __shared__ float prc[256], prs[256], pic[256], pis[256];

    const float fu = (float)(uu - 32) * TIK;

    if (t < HH) {
        float s, c;
        sincosf(fu * ((float)t + 0.5f), &s, &c);
        cb[t] = c;
        sb[t] = s;
    }
    __syncthreads();

    // ---- Phase A: 8 h-groups x 16 h each; float4 over 4 w columns ----
    {
        const int hg = t >> 5;          // 0..7
        const int w4 = (t & 31) << 2;   // 0,4,...,124
        const float4* drow = (const float4*)(dnn + (size_t)b * HH * WW);
        float ar0 = 0, ar1 = 0, ar2 = 0, ar3 = 0;
        float ai0 = 0, ai1 = 0, ai2 = 0, ai3 = 0;
#pragma unroll
        for (int j = 0; j < 16; ++j) {
            const int h = hg * 16 + j;
            const float4 d = drow[h * (WW / 4) + (w4 >> 2)];
            const float ch = cb[h], sh = sb[h];
            ar0 = fmaf(ch, d.x, ar0); ai0 = fmaf(sh, d.x, ai0);
            ar1 = fmaf(ch, d.y, ar1); ai1 = fmaf(sh, d.y, ai1);
            ar2 = fmaf(ch, d.z, ar2); ai2 = fmaf(sh, d.z, ai2);
            ar3 = fmaf(ch, d.w, ar3); ai3 = fmaf(sh, d.w, ai3);
        }
        *(float4*)&a2r[hg * WW + w4] = make_float4(ar0, ar1, ar2, ar3);
        *(float4*)&a2i[hg * WW + w4] = make_float4(ai0, ai1, ai2, ai3);
    }
    __syncthreads();

    if (t < WW) {
        float sr = 0, si = 0;
#pragma unroll
        for (int g = 0; g < 8; ++g) {
            sr += a2r[g * WW + t];
            si += a2i[g * WW + t];
        }
        crw[t] = sr;
        ciw[t] = si;
    }
    __syncthreads();

    // ---- Phase B: rotation recurrence, 4 cross-sums per thread ----
    {
        const int v = t & 63;
        const int q = t >> 6;  // quarter 0..3
        const float fv = (float)(v - 32) * TIK;
        float s0, c0, ss, cs;
        sincosf(fv * ((float)(q * 32) + 0.5f), &s0, &c0);  // angle at w = q*32
        sincosf(fv, &ss, &cs);                              // per-step rotation
        float c = c0, s = s0;
        float rc = 0, rs = 0, ic = 0, is_ = 0;
#pragma unroll
        for (int j = 0; j < 32; ++j) {
            const int w = q * 32 + j;
            const float cr = crw[w], ci = ciw[w];
            rc = fmaf(c, cr, rc);
            rs = fmaf(s, cr, rs);
            ic = fmaf(c, ci, ic);
            is_ = fmaf(s, ci, is_);
            const float cn = fmaf(c, cs, -s * ss);
            s = fmaf(s, cs, c * ss);   // uses old c
            c = cn;
        }
        prc[t] = rc; prs[t] = rs; pic[t] = ic; pis[t] = is_;
    }
    __syncthreads();

    // ---- Combine quarters, emit u and mirror 64-u, squared error ----
    if (t < 64) {
        const float rc = prc[t] + prc[t + 64] + prc[t + 128] + prc[t + 192];
        const float rs = prs[t] + prs[t + 64] + prs[t + 128] + prs[t + 192];
        const float ic = pic[t] + pic[t + 64] + pic[t + 128] + pic[t + 192];
        const float is_ = pis[t] + pis[t + 64] + pis[t + 128] + pis[t + 192];

        const float2 cf = *(const float2*)(chf + ((((size_t)b * S2 + uu) * S2 + t) * 2));
        const float d0 = (rc - is_) - cf.x;   // real(u)
        const float d1 = (rs + ic) - cf.y;    // img(u)
        float sq = fmaf(d0, d0, d1 * d1);

        if (uu >= 1 && uu <= 31) {
            const int um = 64 - uu;
            const float2 cfm = *(const float2*)(chf + ((((size_t)b * S2 + um) * S2 + t) * 2));
            const float d2 = (rc + is_) - cfm.x;  // real(64-u)
            const float d3 = (rs - ic) - cfm.y;   // img(64-u)
            sq = fmaf(d2, d2, sq);
            sq = fmaf(d3, d3, sq);
        }
#pragma unroll
        for (int off = 32; off; off >>= 1)
            sq += __shfl_down(sq, off, 64);
        if (t == 0) partials[bid] = sq;
    }

    cg::this_grid().sync();

    // ---- Block 0 finalizes: per-b sum of 33 partials -> sqrt -> total ----
    if (bid == 0) {
        __shared__ float red[BB];
        if (t < BB) {
            float acc = 0;
            const float* p = partials + (size_t)t * NU;
#pragma unroll
            for (int i = 0; i < NU; ++i) acc += p[i];
            red[t] = sqrtf(acc);
        }
        __syncthreads();
        if (t == 0) {
            float tot = 0;
#pragma unroll
            for (int i = 0; i < BB; ++i) tot += red[i];
            out[0] = tot * (TIK / (float)BB);
        }
    }
}

extern "C" void kernel_launch(void* const* d_in, const int* in_sizes, int n_in,
                              void* d_out, int out_size, void* d_ws, size_t ws_size,
                              hipStream_t stream) {
    const float* dnn = (const float*)d_in[0];  // (16,128,128) f32
    const float* chf = (const float*)d_in[1];  // (16,64,64,2) f32
    float* out = (float*)d_out;                // scalar f32
    float* partials = (float*)d_ws;            // NBLK floats, fully overwritten

    void* args[] = { (void*)&dnn, (void*)&chf, (void*)&partials, (void*)&out };
    hipLaunchCooperativeKernel((void*)chf_fused, dim3(NBLK), dim3(256),
                               args, 0, stream);
}

// Round 4
// 11.824 us; speedup vs baseline: 4.9465x; 4.9465x over previous
//
#include <hip/hip_runtime.h>
#include <math.h>

#define S2 64
#define HH 128
#define WW 128
#define BB 16
#define TIK 0.05f
#define NU 33           // uu = 0..32; uu=1..31 also emit mirror row u = 64-uu
#define NBLK (BB * NU)  // 528 blocks

// One block per (b,uu), 256 threads. NO grid sync (R3 lesson: ~30us).
// freq symmetry: freq[64-u] = -freq[u] => cos even, sin odd, so the 4
// cross-sums (c*Cr, s*Cr, c*Ci, s*Ci) give BOTH u-rows.
__global__ __launch_bounds__(256) void chf_main(const float* __restrict__ dnn,
                                                const float* __restrict__ chf,
                                                float* __restrict__ partials) {
    const int bid = blockIdx.x;
    const int b = bid / NU;
    const int uu = bid - b * NU;     // 0..32
    const int t = threadIdx.x;       // 0..255

    __shared__ float cb[HH], sb[HH];            // cos/sin(fu*(h+0.5))
    __shared__ float a2r[8 * WW], a2i[8 * WW];  // phase-A h-group partials
    __shared__ float crw[WW], ciw[WW];          // stage-A outputs
    __shared__ float prc[256], prs[256], pic[256], pis[256];

    const float fu = (float)(uu - 32) * TIK;

    if (t < HH) {
        float s, c;
        sincosf(fu * ((float)t + 0.5f), &s, &c);
        cb[t] = c;
        sb[t] = s;
    }
    __syncthreads();

    // ---- Phase A: 8 h-groups x 16 h each; float4 over 4 w columns ----
    {
        const int hg = t >> 5;          // 0..7
        const int w4 = (t & 31) << 2;   // 0,4,...,124
        const float4* drow = (const float4*)(dnn + (size_t)b * HH * WW);
        float ar0 = 0, ar1 = 0, ar2 = 0, ar3 = 0;
        float ai0 = 0, ai1 = 0, ai2 = 0, ai3 = 0;
#pragma unroll
        for (int j = 0; j < 16; ++j) {
            const int h = hg * 16 + j;
            const float4 d = drow[h * (WW / 4) + (w4 >> 2)];
            const float ch = cb[h], sh = sb[h];
            ar0 = fmaf(ch, d.x, ar0); ai0 = fmaf(sh, d.x, ai0);
            ar1 = fmaf(ch, d.y, ar1); ai1 = fmaf(sh, d.y, ai1);
            ar2 = fmaf(ch, d.z, ar2); ai2 = fmaf(sh, d.z, ai2);
            ar3 = fmaf(ch, d.w, ar3); ai3 = fmaf(sh, d.w, ai3);
        }
        *(float4*)&a2r[hg * WW + w4] = make_float4(ar0, ar1, ar2, ar3);
        *(float4*)&a2i[hg * WW + w4] = make_float4(ai0, ai1, ai2, ai3);
    }
    __syncthreads();

    if (t < WW) {
        float sr = 0, si = 0;
#pragma unroll
        for (int g = 0; g < 8; ++g) {
            sr += a2r[g * WW + t];
            si += a2i[g * WW + t];
        }
        crw[t] = sr;
        ciw[t] = si;
    }
    __syncthreads();

    // ---- Phase B: rotation recurrence, 4 cross-sums per thread ----
    {
        const int v = t & 63;
        const int q = t >> 6;  // quarter 0..3
        const float fv = (float)(v - 32) * TIK;
        float s0, c0, ss, cs;
        sincosf(fv * ((float)(q * 32) + 0.5f), &s0, &c0);  // angle at w = q*32
        sincosf(fv, &ss, &cs);                              // per-step rotation
        float c = c0, s = s0;
        float rc = 0, rs = 0, ic = 0, is_ = 0;
#pragma unroll
        for (int j = 0; j < 32; ++j) {
            const int w = q * 32 + j;
            const float cr = crw[w], ci = ciw[w];
            rc = fmaf(c, cr, rc);
            rs = fmaf(s, cr, rs);
            ic = fmaf(c, ci, ic);
            is_ = fmaf(s, ci, is_);
            const float cn = fmaf(c, cs, -s * ss);
            s = fmaf(s, cs, c * ss);   // uses old c
            c = cn;
        }
        prc[t] = rc; prs[t] = rs; pic[t] = ic; pis[t] = is_;
    }
    __syncthreads();

    // ---- Combine quarters, emit u and mirror 64-u, squared error ----
    if (t < 64) {
        const float rc = prc[t] + prc[t + 64] + prc[t + 128] + prc[t + 192];
        const float rs = prs[t] + prs[t + 64] + prs[t + 128] + prs[t + 192];
        const float ic = pic[t] + pic[t + 64] + pic[t + 128] + pic[t + 192];
        const float is_ = pis[t] + pis[t + 64] + pis[t + 128] + pis[t + 192];

        const float2 cf = *(const float2*)(chf + ((((size_t)b * S2 + uu) * S2 + t) * 2));
        const float d0 = (rc - is_) - cf.x;   // real(u)
        const float d1 = (rs + ic) - cf.y;    // img(u)
        float sq = fmaf(d0, d0, d1 * d1);

        if (uu >= 1 && uu <= 31) {
            const int um = 64 - uu;
            const float2 cfm = *(const float2*)(chf + ((((size_t)b * S2 + um) * S2 + t) * 2));
            const float d2 = (rc + is_) - cfm.x;  // real(64-u)
            const float d3 = (rs - ic) - cfm.y;   // img(64-u)
            sq = fmaf(d2, d2, sq);
            sq = fmaf(d3, d3, sq);
        }
#pragma unroll
        for (int off = 32; off; off >>= 1)
            sq += __shfl_down(sq, off, 64);
        if (t == 0) partials[bid] = sq;
    }
}

// 1 block x 1024 threads: wave b reduces the 33 partials of batch b.
__global__ __launch_bounds__(1024) void chf_final(const float* __restrict__ partials,
                                                  float* __restrict__ out) {
    const int t = threadIdx.x;   // 0..1023
    const int b = t >> 6;        // wave index = batch
    const int l = t & 63;
    __shared__ float red[BB];
    float v = (l < NU) ? partials[b * NU + l] : 0.0f;
#pragma unroll
    for (int off = 32; off; off >>= 1)
        v += __shfl_down(v, off, 64);
    if (l == 0) red[b] = sqrtf(v);
    __syncthreads();
    if (t == 0) {
        float acc = 0;
#pragma unroll
        for (int i = 0; i < BB; ++i) acc += red[i];
        out[0] = acc * (TIK / (float)BB);
    }
}

extern "C" void kernel_launch(void* const* d_in, const int* in_sizes, int n_in,
                              void* d_out, int out_size, void* d_ws, size_t ws_size,
                              hipStream_t stream) {
    const float* dnn = (const float*)d_in[0];  // (16,128,128) f32
    const float* chf = (const float*)d_in[1];  // (16,64,64,2) f32
    float* out = (float*)d_out;                // scalar f32
    float* partials = (float*)d_ws;            // NBLK floats, fully overwritten

    chf_main<<<dim3(NBLK), dim3(256), 0, stream>>>(dnn, chf, partials);
    chf_final<<<dim3(1), dim3(1024), 0, stream>>>(partials, out);
}